// Round 3
// baseline (158.271 us; speedup 1.0000x reference)
//
#include <hip/hip_runtime.h>
#include <cmath>

// GRU-D cell: B=16384, F=U=512.
//   prep:  xd, hd elementwise -> A1 = [xd|hd] bf16 (B x 1024)
//   pack:  weights -> bf16 B^T (N x K): Wzr (1024x1024), Wht (512x1024)
//   gemm8<0>: A1 @ Wzr -> sigmoid -> Zb (bf16), RH = r*hd (bf16)
//   gemm8<1>: [xd|RH] @ Wht -> tanh, blend with Zb, hd from A1 -> out
// gemm8 = 256x256 tile, BK=64, 8 waves (2Mx4N), 4-phase/K-tile schedule,
// counted vmcnt(6), XOR-16B LDS swizzle, raw s_barrier, setprio MFMA clusters.
// R3: LDS reads via typed __shared__ indexing (force ds_read_b128, not flat).

typedef __bf16 bf16x8 __attribute__((ext_vector_type(8)));
typedef __bf16 bf16x4 __attribute__((ext_vector_type(4)));
typedef float f32x4 __attribute__((ext_vector_type(4)));

typedef __attribute__((address_space(3))) void lds_vp;
typedef const __attribute__((address_space(1))) void g_vp;

#define VMC(N) asm volatile("s_waitcnt vmcnt(" N ")" ::: "memory")

__device__ __forceinline__ void barrier_() {
  asm volatile("" ::: "memory");
  __builtin_amdgcn_s_barrier();
  asm volatile("" ::: "memory");
}

__device__ __forceinline__ float sigmoidf_(float x) { return 1.f / (1.f + expf(-x)); }

// ---------------- prep ----------------
__global__ __launch_bounds__(256) void prep_k(
    const float* __restrict__ inp, const float* __restrict__ h_prev,
    const float* __restrict__ gxd, const float* __restrict__ ghd,
    const float* __restrict__ mimp, __bf16* __restrict__ A1) {
  int idx = blockIdx.x * 256 + threadIdx.x;
  int row = idx >> 7;
  int c4 = (idx & 127) << 2;
  const float4 x  = *(const float4*)(inp + (size_t)row * 1536 + c4);
  const float4 mm = *(const float4*)(inp + (size_t)row * 1536 + 512 + c4);
  const float4 dt = *(const float4*)(inp + (size_t)row * 1536 + 1024 + c4);
  const float4 gx = *(const float4*)(gxd + c4);
  const float4 gh = *(const float4*)(ghd + c4);
  const float4 mi = *(const float4*)(mimp + c4);
  const float4 hp = *(const float4*)(h_prev + (size_t)row * 512 + c4);
  bf16x4 xo, ho;
#pragma unroll
  for (int j = 0; j < 4; ++j) {
    float xx = ((const float*)&x)[j];
    float m  = ((const float*)&mm)[j];
    float d  = ((const float*)&dt)[j];
    float g  = expf(-fmaxf(0.f, ((const float*)&gx)[j]) * d);
    float xd = m * xx + (1.f - m) * (g * xx + (1.f - g) * ((const float*)&mi)[j]);
    float gg = expf(-fmaxf(0.f, ((const float*)&gh)[j]) * d);
    float hd = gg * ((const float*)&hp)[j];
    xo[j] = (__bf16)xd;
    ho[j] = (__bf16)hd;
  }
  *(bf16x4*)(A1 + (size_t)row * 1024 + c4) = xo;
  *(bf16x4*)(A1 + (size_t)row * 1024 + 512 + c4) = ho;
}

// ---------------- pack ----------------
__global__ __launch_bounds__(256) void pack_k(
    const float* __restrict__ Wz, const float* __restrict__ Uz,
    const float* __restrict__ Wr, const float* __restrict__ Ur,
    const float* __restrict__ Wh, const float* __restrict__ Uh,
    __bf16* __restrict__ Wzr, __bf16* __restrict__ Wht) {
  int id = blockIdx.x * 256 + threadIdx.x;
  if (id < 1024 * 1024) {
    int n = id >> 10, k = id & 1023;
    float v;
    if (n < 512) v = (k < 512) ? Wz[k * 512 + n] : Uz[(k - 512) * 512 + n];
    else         v = (k < 512) ? Wr[k * 512 + (n - 512)] : Ur[(k - 512) * 512 + (n - 512)];
    Wzr[id] = (__bf16)v;
  } else {
    int id2 = id - 1024 * 1024;
    int n = id2 >> 10, k = id2 & 1023;
    float v = (k < 512) ? Wh[k * 512 + n] : Uh[(k - 512) * 512 + n];
    Wht[id2] = (__bf16)v;
  }
}

// ---------------- 8-wave 256x256 GEMM ----------------
// stage one 8KB quarter: 8 waves x 8 rows x 128B, linear LDS dest,
// inverse-swizzled global source (LDS[r][o] holds global (r, o^((r&7)<<4))).
__device__ __forceinline__ void stage_q(const char* g, int ldb, char* ldst,
                                        int rowbase, int lane) {
  int r = rowbase + (lane >> 3);
  int c = (((lane & 7) ^ (lane >> 3)) << 4);
  __builtin_amdgcn_global_load_lds((g_vp*)(g + (size_t)r * ldb + c),
                                   (lds_vp*)(ldst + rowbase * 128), 16, 0, 0);
}

#define MFMA16(MB, NB, BF)                                                     \
  __builtin_amdgcn_s_setprio(1);                                               \
  _Pragma("unroll") for (int mi = 0; mi < 4; ++mi)                             \
  _Pragma("unroll") for (int ni = 0; ni < 2; ++ni) {                           \
    acc[(MB) + mi][(NB) + ni] = __builtin_amdgcn_mfma_f32_16x16x32_bf16(       \
        af[mi * 2 + 0], BF[ni * 2 + 0], acc[(MB) + mi][(NB) + ni], 0, 0, 0);   \
    acc[(MB) + mi][(NB) + ni] = __builtin_amdgcn_mfma_f32_16x16x32_bf16(       \
        af[mi * 2 + 1], BF[ni * 2 + 1], acc[(MB) + mi][(NB) + ni], 0, 0, 0);   \
  }                                                                            \
  __builtin_amdgcn_s_setprio(0);

template <int MODE>
__global__ __launch_bounds__(512, 2) void gemm8_k(
    const __bf16* __restrict__ A1, const __bf16* __restrict__ RH,
    const __bf16* __restrict__ Bt,
    __bf16* __restrict__ Zb, __bf16* __restrict__ RHout,
    const float* __restrict__ bza, const float* __restrict__ bzb,
    float* __restrict__ out) {
  // 131072 B = [buf p][A 32KB | B 32KB], addressed in 16B units.
  __shared__ bf16x8 ldsv[8192];
  constexpr int NT = 16;
  constexpr int NBN = (MODE == 0) ? 4 : 2;
  constexpr int CPX = ((MODE == 0) ? 256 : 128) / 8;
  int bid = blockIdx.x;
  int swz = (bid & 7) * CPX + (bid >> 3);   // bijective XCD swizzle
  int bm = swz / NBN, bn = swz % NBN;
  int tid = threadIdx.x, lane = tid & 63, wid = tid >> 6;
  int wm = wid >> 2, wn = wid & 3;

  auto stageA = [&](int t, int half) {  // half 0: rows{0-63,128-191}, 1: +64
    const char* g;
    int ldb;
    if (MODE == 0 || t < 8) {
      g = (const char*)A1 + (size_t)bm * 256 * 2048 + t * 128;
      ldb = 2048;
    } else {
      g = (const char*)RH + (size_t)bm * 256 * 1024 + (t - 8) * 128;
      ldb = 1024;
    }
    char* ldst = (char*)ldsv + ((t & 1) ? 65536 : 0);
    int rb = half * 64 + wid * 8;
    stage_q(g, ldb, ldst, rb, lane);
    stage_q(g, ldb, ldst, rb + 128, lane);
  };
  auto stageB = [&](int t, int nhalf) {  // nhalf 0: n0-1 rows, 1: n2-3 rows
    const char* g = (const char*)Bt + (size_t)bn * 256 * 2048 + t * 128;
    char* ldst = (char*)ldsv + ((t & 1) ? 65536 : 0) + 32768;
    int rb = (wid & 3) * 8 + (wid >> 2) * 64 + nhalf * 32;
    stage_q(g, 2048, ldst, rb, lane);
    stage_q(g, 2048, ldst, rb + 128, lane);
  };

  // ds_read element indices (16B units), swizzled col
  int colx0 = (lane >> 4) ^ (lane & 7);
  int colx1 = ((lane >> 4) + 4) ^ (lane & 7);
  int aB = wm * 1024 + (lane & 15) * 8;          // + pb + mi*128 + colx
  int bB = 2048 + wn * 512 + (lane & 15) * 8;    // + pb + ni*128 + colx

  f32x4 acc[8][4] = {};

  // prologue: tile0 full, tile1 all but Bn01
  stageA(0, 0); stageB(0, 1); stageA(0, 1); stageB(0, 0);
  stageA(1, 0); stageB(1, 1); stageA(1, 1);
  VMC("6");
  barrier_();

  for (int t = 0; t < NT; ++t) {
    int pb = (t & 1) ? 4096 : 0;
    bf16x8 af[8], b01[4], b23[4];

    // ---- phase 1: A(m0-3), B(n0-1); stage Bn01(t+1) -> other buf ----
#pragma unroll
    for (int mi = 0; mi < 4; ++mi) {
      af[mi * 2 + 0] = ldsv[pb + aB + mi * 128 + colx0];
      af[mi * 2 + 1] = ldsv[pb + aB + mi * 128 + colx1];
    }
#pragma unroll
    for (int ni = 0; ni < 2; ++ni) {
      b01[ni * 2 + 0] = ldsv[pb + bB + ni * 128 + colx0];
      b01[ni * 2 + 1] = ldsv[pb + bB + ni * 128 + colx1];
    }
    if (t + 1 < NT) stageB(t + 1, 0);
    barrier_();
    MFMA16(0, 0, b01);
    barrier_();
    // ---- phase 2: B(n2-3); stage A q02(t+2) -> this buf ----
#pragma unroll
    for (int ni = 0; ni < 2; ++ni) {
      b23[ni * 2 + 0] = ldsv[pb + bB + (2 + ni) * 128 + colx0];
      b23[ni * 2 + 1] = ldsv[pb + bB + (2 + ni) * 128 + colx1];
    }
    if (t + 2 < NT) stageA(t + 2, 0);
    barrier_();
    MFMA16(0, 2, b23);
    barrier_();
    // ---- phase 3: A(m4-7); stage Bn23(t+2) -> this buf ----
#pragma unroll
    for (int mi = 0; mi < 4; ++mi) {
      af[mi * 2 + 0] = ldsv[pb + aB + (4 + mi) * 128 + colx0];
      af[mi * 2 + 1] = ldsv[pb + aB + (4 + mi) * 128 + colx1];
    }
    if (t + 2 < NT) stageB(t + 2, 1);
    barrier_();
    MFMA16(4, 2, b23);
    barrier_();
    // ---- phase 4: b01 still in regs; stage A q13(t+2); counted vmcnt ----
    if (t + 2 < NT) stageA(t + 2, 1);
    if (t < NT - 2) { VMC("6"); } else if (t == NT - 2) { VMC("0"); }
    barrier_();
    MFMA16(4, 0, b01);
    barrier_();
  }

  // ---------------- epilogue ----------------
  int col16 = lane & 15, rgrp = lane >> 4;
#pragma unroll
  for (int m = 0; m < 8; ++m) {
    int grow0 = bm * 256 + wm * 128 + m * 16 + rgrp * 4;
#pragma unroll
    for (int n = 0; n < 4; ++n) {
      int gc = bn * 256 + wn * 64 + n * 16 + col16;
      if constexpr (MODE == 0) {
        if (bn < 2) {  // z columns (block-uniform)
          float b = bza[gc];
#pragma unroll
          for (int j = 0; j < 4; ++j) {
            float z = sigmoidf_(acc[m][n][j] + b);
            Zb[(size_t)(grow0 + j) * 512 + gc] = (__bf16)z;
          }
        } else {       // r columns
          int c = gc - 512;
          float b = bzb[c];
#pragma unroll
          for (int j = 0; j < 4; ++j) {
            int grow = grow0 + j;
            float r = sigmoidf_(acc[m][n][j] + b);
            float hd = (float)A1[(size_t)grow * 1024 + 512 + c];
            RHout[(size_t)grow * 512 + c] = (__bf16)(r * hd);
          }
        }
      } else {
        float b = bza[gc];
#pragma unroll
        for (int j = 0; j < 4; ++j) {
          int grow = grow0 + j;
          float hh = tanhf(acc[m][n][j] + b);
          float hd = (float)A1[(size_t)grow * 1024 + 512 + gc];
          float z = (float)Zb[(size_t)grow * 512 + gc];
          out[(size_t)grow * 512 + gc] = (1.f - z) * hd + z * hh;
        }
      }
    }
  }
}

// ---------------- launch ----------------
extern "C" void kernel_launch(void* const* d_in, const int* in_sizes, int n_in,
                              void* d_out, int out_size, void* d_ws, size_t ws_size,
                              hipStream_t stream) {
  const float* inputs = (const float*)d_in[0];
  const float* h_prev = (const float*)d_in[1];
  const float* W_z = (const float*)d_in[2];
  const float* U_z = (const float*)d_in[3];
  const float* b_z = (const float*)d_in[4];
  const float* W_r = (const float*)d_in[5];
  const float* U_r = (const float*)d_in[6];
  const float* b_r = (const float*)d_in[7];
  const float* W_h = (const float*)d_in[8];
  const float* U_h = (const float*)d_in[9];
  const float* b_h = (const float*)d_in[10];
  const float* gxd = (const float*)d_in[11];
  const float* ghd = (const float*)d_in[12];
  const float* mimp = (const float*)d_in[13];
  float* out = (float*)d_out;

  char* ws = (char*)d_ws;
  __bf16* A1  = (__bf16*)(ws);                  // 16384x1024 bf16 = 32MB
  __bf16* RH  = (__bf16*)(ws + 33554432);       // 16384x512 bf16 = 16MB
  __bf16* Zb  = (__bf16*)(ws + 50331648);       // 16384x512 bf16 = 16MB
  __bf16* Wzr = (__bf16*)(ws + 67108864);       // 1024x1024 bf16 = 2MB
  __bf16* Wht = (__bf16*)(ws + 69206016);       // 512x1024 bf16  = 1MB

  prep_k<<<8192, 256, 0, stream>>>(inputs, h_prev, gxd, ghd, mimp, A1);
  pack_k<<<6144, 256, 0, stream>>>(W_z, U_z, W_r, U_r, W_h, U_h, Wzr, Wht);
  gemm8_k<0><<<256, 512, 0, stream>>>(A1, RH, Wzr, Zb, RH, b_z, b_r, nullptr);
  gemm8_k<1><<<128, 512, 0, stream>>>(A1, RH, Wht, Zb, nullptr, b_h, nullptr, out);
}

// Round 4
// 125.683 us; speedup vs baseline: 1.2593x; 1.2593x over previous
//
#include <hip/hip_runtime.h>
#include <cmath>

// GRU-D cell: B=16384, F=U=512.
//   prep:  xd, hd elementwise -> A1 = [xd|hd] bf16 (B x 1024)
//   pack:  weights -> bf16 B^T (N x K): Wzr (1024x1024), Wht (512x1024)
//   gemm2<0>: A1 @ Wzr -> sigmoid -> Zb (bf16), RH = r*hd (bf16)   [256x256]
//   gemm2<1>: [xd|RH] @ Wht -> tanh, blend with Zb, hd from A1 -> out [256x128]
// R4: catalog-verified "minimum 2-phase" schedule: per K-tile
//   { stage(next buf); ds_read all frags; MFMA cluster; vmcnt(0); barrier }
// ONE barrier + one vm-drain per tile (R3's 8-phase lockstep had 8 barriers
// per tile and ran at 8% MfmaUtil). XOR-16B swizzle retained (proven R2/R3).

typedef __bf16 bf16x8 __attribute__((ext_vector_type(8)));
typedef __bf16 bf16x4 __attribute__((ext_vector_type(4)));
typedef float f32x4 __attribute__((ext_vector_type(4)));

typedef __attribute__((address_space(3))) void lds_vp;
typedef const __attribute__((address_space(1))) void g_vp;

#define VMC(N) asm volatile("s_waitcnt vmcnt(" N ")" ::: "memory")

__device__ __forceinline__ void barrier_() {
  asm volatile("" ::: "memory");
  __builtin_amdgcn_s_barrier();
  asm volatile("" ::: "memory");
}

__device__ __forceinline__ float sigmoidf_(float x) { return 1.f / (1.f + expf(-x)); }

// ---------------- prep ----------------
__global__ __launch_bounds__(256) void prep_k(
    const float* __restrict__ inp, const float* __restrict__ h_prev,
    const float* __restrict__ gxd, const float* __restrict__ ghd,
    const float* __restrict__ mimp, __bf16* __restrict__ A1) {
  int idx = blockIdx.x * 256 + threadIdx.x;
  int row = idx >> 7;
  int c4 = (idx & 127) << 2;
  const float4 x  = *(const float4*)(inp + (size_t)row * 1536 + c4);
  const float4 mm = *(const float4*)(inp + (size_t)row * 1536 + 512 + c4);
  const float4 dt = *(const float4*)(inp + (size_t)row * 1536 + 1024 + c4);
  const float4 gx = *(const float4*)(gxd + c4);
  const float4 gh = *(const float4*)(ghd + c4);
  const float4 mi = *(const float4*)(mimp + c4);
  const float4 hp = *(const float4*)(h_prev + (size_t)row * 512 + c4);
  bf16x4 xo, ho;
#pragma unroll
  for (int j = 0; j < 4; ++j) {
    float xx = ((const float*)&x)[j];
    float m  = ((const float*)&mm)[j];
    float d  = ((const float*)&dt)[j];
    float g  = expf(-fmaxf(0.f, ((const float*)&gx)[j]) * d);
    float xd = m * xx + (1.f - m) * (g * xx + (1.f - g) * ((const float*)&mi)[j]);
    float gg = expf(-fmaxf(0.f, ((const float*)&gh)[j]) * d);
    float hd = gg * ((const float*)&hp)[j];
    xo[j] = (__bf16)xd;
    ho[j] = (__bf16)hd;
  }
  *(bf16x4*)(A1 + (size_t)row * 1024 + c4) = xo;
  *(bf16x4*)(A1 + (size_t)row * 1024 + 512 + c4) = ho;
}

// ---------------- pack ----------------
__global__ __launch_bounds__(256) void pack_k(
    const float* __restrict__ Wz, const float* __restrict__ Uz,
    const float* __restrict__ Wr, const float* __restrict__ Ur,
    const float* __restrict__ Wh, const float* __restrict__ Uh,
    __bf16* __restrict__ Wzr, __bf16* __restrict__ Wht) {
  int id = blockIdx.x * 256 + threadIdx.x;
  if (id < 1024 * 1024) {
    int n = id >> 10, k = id & 1023;
    float v;
    if (n < 512) v = (k < 512) ? Wz[k * 512 + n] : Uz[(k - 512) * 512 + n];
    else         v = (k < 512) ? Wr[k * 512 + (n - 512)] : Ur[(k - 512) * 512 + (n - 512)];
    Wzr[id] = (__bf16)v;
  } else {
    int id2 = id - 1024 * 1024;
    int n = id2 >> 10, k = id2 & 1023;
    float v = (k < 512) ? Wh[k * 512 + n] : Uh[(k - 512) * 512 + n];
    Wht[id2] = (__bf16)v;
  }
}

// ---------------- 2-phase 8-wave GEMM ----------------
// stage one 8-row x 128B group: linear LDS dest, inverse-swizzled global src
// (LDS[r][u] (16B units) holds global (r, u ^ (r&7))).
__device__ __forceinline__ void stage_q(const char* g, int ldb, char* ldst,
                                        int rowbase, int lane) {
  int r = rowbase + (lane >> 3);
  int c = (((lane & 7) ^ (lane >> 3)) << 4);
  __builtin_amdgcn_global_load_lds((g_vp*)(g + (size_t)r * ldb + c),
                                   (lds_vp*)(ldst + rowbase * 128), 16, 0, 0);
}

template <int MODE>
__global__ __launch_bounds__(512, 2) void gemm2_k(
    const __bf16* __restrict__ A1, const __bf16* __restrict__ RH,
    const __bf16* __restrict__ Bt,
    __bf16* __restrict__ Zb, __bf16* __restrict__ RHout,
    const float* __restrict__ bza, const float* __restrict__ bzb,
    float* __restrict__ out) {
  constexpr int NI = (MODE == 0) ? 4 : 2;        // B-frags per wave (BN/64)
  constexpr int BN = NI * 64;
  constexpr int SBUF = 2048 + BN * 8;            // 16B units per buffer
  __shared__ bf16x8 ldsv[2 * SBUF];
  constexpr int NT = 16;

  int bid = blockIdx.x;
  int swz = (bid & 7) * 32 + (bid >> 3);         // bijective XCD swizzle (256=8x32)
  int bm = swz >> 2, bn = swz & 3;
  int tid = threadIdx.x, lane = tid & 63, wid = tid >> 6;
  int wm = wid >> 2, wn = wid & 3;

  auto stage = [&](int t, int buf) {
    const char* gA;
    int ldbA;
    if (MODE == 0 || t < 8) {
      gA = (const char*)A1 + (size_t)bm * 256 * 2048 + t * 128;
      ldbA = 2048;
    } else {
      gA = (const char*)RH + (size_t)bm * 256 * 1024 + (t - 8) * 128;
      ldbA = 1024;
    }
    char* ldstA = (char*)(ldsv + buf * SBUF);
#pragma unroll
    for (int i = 0; i < 4; ++i) stage_q(gA, ldbA, ldstA, i * 64 + wid * 8, lane);
    const char* gB = (const char*)Bt + (size_t)bn * BN * 2048 + t * 128;
    char* ldstB = (char*)(ldsv + buf * SBUF + 2048);
#pragma unroll
    for (int i = 0; i < NI; ++i) stage_q(gB, 2048, ldstB, i * 64 + wid * 8, lane);
  };

  // swizzled read cols (16B units)
  int colx0 = (lane >> 4) ^ (lane & 7);
  int colx1 = ((lane >> 4) + 4) ^ (lane & 7);
  int aB = wm * 1024 + (lane & 15) * 8;               // + mi*128 + colx
  int bB = 2048 + wn * (NI * 128) + (lane & 15) * 8;  // + ni*128 + colx

  f32x4 acc[8][NI] = {};

  stage(0, 0);
  VMC("0");
  barrier_();

  int cur = 0;
  for (int t = 0; t < NT; ++t) {
    if (t + 1 < NT) stage(t + 1, cur ^ 1);
    int base = cur * SBUF;

    bf16x8 bf[2 * NI];
#pragma unroll
    for (int ni = 0; ni < NI; ++ni) {
      bf[ni * 2 + 0] = ldsv[base + bB + ni * 128 + colx0];
      bf[ni * 2 + 1] = ldsv[base + bB + ni * 128 + colx1];
    }
    __builtin_amdgcn_s_setprio(1);
#pragma unroll
    for (int mi = 0; mi < 8; ++mi) {
      bf16x8 a0 = ldsv[base + aB + mi * 128 + colx0];
      bf16x8 a1 = ldsv[base + aB + mi * 128 + colx1];
#pragma unroll
      for (int ni = 0; ni < NI; ++ni) {
        acc[mi][ni] = __builtin_amdgcn_mfma_f32_16x16x32_bf16(a0, bf[ni * 2 + 0],
                                                              acc[mi][ni], 0, 0, 0);
        acc[mi][ni] = __builtin_amdgcn_mfma_f32_16x16x32_bf16(a1, bf[ni * 2 + 1],
                                                              acc[mi][ni], 0, 0, 0);
      }
    }
    __builtin_amdgcn_s_setprio(0);

    if (t + 1 < NT) {
      VMC("0");     // next-tile stage complete (issued a full tile ago)
      barrier_();   // all waves done reading buf[cur]
    }
    cur ^= 1;
  }

  // ---------------- epilogue ----------------
  int col16 = lane & 15, rgrp = lane >> 4;
#pragma unroll
  for (int m = 0; m < 8; ++m) {
    int grow0 = bm * 256 + wm * 128 + m * 16 + rgrp * 4;
#pragma unroll
    for (int n = 0; n < NI; ++n) {
      int gc = bn * BN + wn * (NI * 16) + n * 16 + col16;
      if constexpr (MODE == 0) {
        if (bn < 2) {  // z columns (block-uniform: BN=256 divides 512)
          float b = bza[gc];
#pragma unroll
          for (int j = 0; j < 4; ++j) {
            float z = sigmoidf_(acc[m][n][j] + b);
            Zb[(size_t)(grow0 + j) * 512 + gc] = (__bf16)z;
          }
        } else {       // r columns
          int c = gc - 512;
          float b = bzb[c];
#pragma unroll
          for (int j = 0; j < 4; ++j) {
            int grow = grow0 + j;
            float r = sigmoidf_(acc[m][n][j] + b);
            float hd = (float)A1[(size_t)grow * 1024 + 512 + c];
            RHout[(size_t)grow * 512 + c] = (__bf16)(r * hd);
          }
        }
      } else {
        float b = bza[gc];
#pragma unroll
        for (int j = 0; j < 4; ++j) {
          int grow = grow0 + j;
          float hh = tanhf(acc[m][n][j] + b);
          float hd = (float)A1[(size_t)grow * 1024 + 512 + gc];
          float z = (float)Zb[(size_t)grow * 512 + gc];
          out[(size_t)grow * 512 + gc] = (1.f - z) * hd + z * hh;
        }
      }
    }
  }
}

// ---------------- launch ----------------
extern "C" void kernel_launch(void* const* d_in, const int* in_sizes, int n_in,
                              void* d_out, int out_size, void* d_ws, size_t ws_size,
                              hipStream_t stream) {
  const float* inputs = (const float*)d_in[0];
  const float* h_prev = (const float*)d_in[1];
  const float* W_z = (const float*)d_in[2];
  const float* U_z = (const float*)d_in[3];
  const float* b_z = (const float*)d_in[4];
  const float* W_r = (const float*)d_in[5];
  const float* U_r = (const float*)d_in[6];
  const float* b_r = (const float*)d_in[7];
  const float* W_h = (const float*)d_in[8];
  const float* U_h = (const float*)d_in[9];
  const float* b_h = (const float*)d_in[10];
  const float* gxd = (const float*)d_in[11];
  const float* ghd = (const float*)d_in[12];
  const float* mimp = (const float*)d_in[13];
  float* out = (float*)d_out;

  char* ws = (char*)d_ws;
  __bf16* A1  = (__bf16*)(ws);                  // 16384x1024 bf16 = 32MB
  __bf16* RH  = (__bf16*)(ws + 33554432);       // 16384x512 bf16 = 16MB
  __bf16* Zb  = (__bf16*)(ws + 50331648);       // 16384x512 bf16 = 16MB
  __bf16* Wzr = (__bf16*)(ws + 67108864);       // 1024x1024 bf16 = 2MB
  __bf16* Wht = (__bf16*)(ws + 69206016);       // 512x1024 bf16  = 1MB

  prep_k<<<8192, 256, 0, stream>>>(inputs, h_prev, gxd, ghd, mimp, A1);
  pack_k<<<6144, 256, 0, stream>>>(W_z, U_z, W_r, U_r, W_h, U_h, Wzr, Wht);
  gemm2_k<0><<<256, 512, 0, stream>>>(A1, RH, Wzr, Zb, RH, b_z, b_r, nullptr);
  gemm2_k<1><<<256, 512, 0, stream>>>(A1, RH, Wht, Zb, nullptr, b_h, nullptr, out);
}